// Round 1
// baseline (288.818 us; speedup 1.0000x reference)
//
#include <hip/hip_runtime.h>

// GCN 2-layer forward on MI355X.
// Strategy: CSR-by-dst counting sort each call (graph-capture safe, no host work),
// dinv folded into features, layer1 agg fused with GEMM2, LDS-histogram pooling.

#define NGRAPH 64
#define CH 128

// ---------------- init ----------------
__global__ void k_init(int* __restrict__ deg, int* __restrict__ row_start,
                       float* __restrict__ gsum, int* __restrict__ gcnt,
                       int N, int E) {
    int i = blockIdx.x * blockDim.x + threadIdx.x;
    if (i < N) deg[i] = 1;                 // self-loop
    if (i == 0) row_start[N] = E;          // sentinel
    if (i < 2 * NGRAPH) gsum[i] = 0.f;
    if (i < NGRAPH) gcnt[i] = 0;
}

// ---------------- degree count ----------------
__global__ void k_count(const int* __restrict__ dst, int* __restrict__ deg, int E) {
    int i = blockIdx.x * blockDim.x + threadIdx.x;
    if (i < E) atomicAdd(&deg[dst[i]], 1);
}

__global__ void k_dinv(const int* __restrict__ deg, float* __restrict__ dinv, int N) {
    int i = blockIdx.x * blockDim.x + threadIdx.x;
    if (i < N) dinv[i] = rsqrtf((float)deg[i]);
}

// ---------------- exclusive scan of (deg-1) over N elements, 3 passes ----------------
__global__ void k_scan_a(const int* __restrict__ deg, int* __restrict__ row_start,
                         int* __restrict__ bsum, int N) {
    __shared__ int tmp[256];
    int t = threadIdx.x;
    int i = blockIdx.x * 256 + t;
    int v = (i < N) ? (deg[i] - 1) : 0;   // edge count excluding self-loop
    int val = v;
    tmp[t] = val;
    __syncthreads();
    for (int off = 1; off < 256; off <<= 1) {
        int add = (t >= off) ? tmp[t - off] : 0;
        __syncthreads();
        val += add;
        tmp[t] = val;
        __syncthreads();
    }
    if (i < N) row_start[i] = val - v;     // exclusive
    if (t == 255) bsum[blockIdx.x] = val;  // block total
}

__global__ void k_scan_b(const int* __restrict__ bsum, int* __restrict__ boff, int nb) {
    __shared__ int tmp[256];
    int t = threadIdx.x;
    int v = (t < nb) ? bsum[t] : 0;
    int val = v;
    tmp[t] = val;
    __syncthreads();
    for (int off = 1; off < 256; off <<= 1) {
        int add = (t >= off) ? tmp[t - off] : 0;
        __syncthreads();
        val += add;
        tmp[t] = val;
        __syncthreads();
    }
    if (t < nb) boff[t] = val - v;
}

__global__ void k_scan_c(int* __restrict__ row_start, int* __restrict__ cursor,
                         const int* __restrict__ boff, int N) {
    int i = blockIdx.x * blockDim.x + threadIdx.x;
    if (i < N) {
        int rs = row_start[i] + boff[blockIdx.x * blockDim.x / 256 + (threadIdx.x >= 256 ? 1 : 0)];
        // blockDim==256 so the above reduces to boff[blockIdx.x]; keep simple:
        rs = row_start[i] + boff[i / 256];
        row_start[i] = rs;
        cursor[i] = rs;
    }
}

// ---------------- CSR fill (counting sort by dst) ----------------
__global__ void k_fill(const int* __restrict__ src, const int* __restrict__ dst,
                       int* __restrict__ cursor, int* __restrict__ csr, int E) {
    int i = blockIdx.x * blockDim.x + threadIdx.x;
    if (i < E) {
        int d = dst[i];
        int p = atomicAdd(&cursor[d], 1);
        csr[p] = src[i];
    }
}

// ---------------- GEMM1: h[n] = (x[n] @ W1) * dinv[n]  (f32 vector ALU) ----------------
__global__ __launch_bounds__(256) void k_gemm1(const float* __restrict__ X,
                                               const float* __restrict__ W,
                                               const float* __restrict__ dinv,
                                               float* __restrict__ H, int N) {
    __shared__ float xs[32][CH];
    int tid = threadIdx.x;
    int row0 = blockIdx.x * 32;
    // stage 32x128 X tile (1024 float4, 16B/lane coalesced)
    for (int i = tid; i < 1024; i += 256) {
        int r = i >> 5;
        int c4 = i & 31;
        int gr = row0 + r;
        float4 v = (gr < N) ? ((const float4*)X)[(size_t)gr * 32 + c4]
                            : make_float4(0.f, 0.f, 0.f, 0.f);
        *((float4*)&xs[r][c4 * 4]) = v;
    }
    __syncthreads();
    int tx = tid & 31;   // 4 cols each: c0 = tx*4
    int ty = tid >> 5;   // 4 rows each: r0 = ty*4
    float acc[4][4] = {};
    #pragma unroll 4
    for (int k4 = 0; k4 < CH; k4 += 4) {
        float4 xv[4];
        #pragma unroll
        for (int r = 0; r < 4; r++)
            xv[r] = *(const float4*)&xs[ty * 4 + r][k4];
        #pragma unroll
        for (int kk = 0; kk < 4; kk++) {
            float4 wv = *(const float4*)(W + (size_t)(k4 + kk) * CH + tx * 4);
            #pragma unroll
            for (int r = 0; r < 4; r++) {
                float xr = (kk == 0) ? xv[r].x : (kk == 1) ? xv[r].y : (kk == 2) ? xv[r].z : xv[r].w;
                acc[r][0] = fmaf(xr, wv.x, acc[r][0]);
                acc[r][1] = fmaf(xr, wv.y, acc[r][1]);
                acc[r][2] = fmaf(xr, wv.z, acc[r][2]);
                acc[r][3] = fmaf(xr, wv.w, acc[r][3]);
            }
        }
    }
    #pragma unroll
    for (int r = 0; r < 4; r++) {
        int gr = row0 + ty * 4 + r;
        if (gr < N) {
            float dv = dinv[gr];
            float4 o = make_float4(acc[r][0] * dv, acc[r][1] * dv, acc[r][2] * dv, acc[r][3] * dv);
            *(float4*)(H + (size_t)gr * CH + tx * 4) = o;
        }
    }
}

// ---------------- layer1 aggregate + bias + relu + GEMM2 fused ----------------
// one block (128 threads) per node; thread l = channel l.
// h holds (x@W1)*dinv[src]; output h2[n] = (relu(dinv[n]*sum + b1) @ W2) * dinv[n]
__global__ __launch_bounds__(128) void k_layer1(const float* __restrict__ h,
                                                const int* __restrict__ csr,
                                                const int* __restrict__ row_start,
                                                const float* __restrict__ dinv,
                                                const float* __restrict__ b1,
                                                const float* __restrict__ W2,
                                                float* __restrict__ h2, int N) {
    __shared__ int s_off[128];
    __shared__ float s_red[4];
    int n = blockIdx.x;
    if (n >= N) return;
    int l = threadIdx.x;          // channel
    float dn = dinv[n];
    int base = row_start[n];
    int cnt = row_start[n + 1] - base;
    float acc = h[(size_t)n * CH + l];   // self-loop term (already *dinv[n])
    for (int c0 = 0; c0 < cnt; c0 += 128) {
        int m = min(128, cnt - c0);
        if (l < m) s_off[l] = csr[base + c0 + l] * CH;
        __syncthreads();
        for (int j = 0; j < m; j++)
            acc += h[(size_t)s_off[j] + l];   // coalesced 512B row gather
        __syncthreads();
    }
    float v = fmaxf(fmaf(dn, acc, b1[l]), 0.f);   // conv1 out + bias, relu
    float p0 = v * W2[l * 2 + 0];
    float p1 = v * W2[l * 2 + 1];
    #pragma unroll
    for (int off = 32; off > 0; off >>= 1) {      // 64-lane wave reduce
        p0 += __shfl_down(p0, off);
        p1 += __shfl_down(p1, off);
    }
    if ((l & 63) == 0) {
        s_red[(l >> 6) * 2 + 0] = p0;
        s_red[(l >> 6) * 2 + 1] = p1;
    }
    __syncthreads();
    if (l == 0) {
        h2[n * 2 + 0] = (s_red[0] + s_red[2]) * dn;   // pre-scale by dinv[n] for layer2
        h2[n * 2 + 1] = (s_red[1] + s_red[3]) * dn;
    }
}

// ---------------- layer2 aggregate + global mean pool accumulate ----------------
__global__ __launch_bounds__(256) void k_layer2_pool(const float* __restrict__ h2,
                                                     const int* __restrict__ csr,
                                                     const int* __restrict__ row_start,
                                                     const float* __restrict__ dinv,
                                                     const int* __restrict__ batch,
                                                     float* __restrict__ gsum,
                                                     int* __restrict__ gcnt, int N) {
    __shared__ float ssum[2 * NGRAPH];
    __shared__ int scnt[NGRAPH];
    int t = threadIdx.x;
    if (t < 2 * NGRAPH) ssum[t] = 0.f;
    if (t < NGRAPH) scnt[t] = 0;
    __syncthreads();
    int n = blockIdx.x * blockDim.x + t;
    if (n < N) {
        float dn = dinv[n];
        float a0 = h2[n * 2 + 0];
        float a1 = h2[n * 2 + 1];
        int base = row_start[n], end = row_start[n + 1];
        for (int e = base; e < end; e++) {
            int s = csr[e];
            a0 += h2[s * 2 + 0];
            a1 += h2[s * 2 + 1];
        }
        a0 *= dn;
        a1 *= dn;
        int g = batch[n];
        atomicAdd(&ssum[g * 2 + 0], a0);
        atomicAdd(&ssum[g * 2 + 1], a1);
        atomicAdd(&scnt[g], 1);
    }
    __syncthreads();
    if (t < 2 * NGRAPH) atomicAdd(&gsum[t], ssum[t]);
    if (t < NGRAPH) atomicAdd(&gcnt[t], scnt[t]);
}

__global__ void k_final(const float* __restrict__ gsum, const int* __restrict__ gcnt,
                        const float* __restrict__ b2, float* __restrict__ out) {
    int t = threadIdx.x;   // 0..127
    if (t < 2 * NGRAPH) {
        int g = t >> 1, c = t & 1;
        float cnt = fmaxf((float)gcnt[g], 1.f);
        out[t] = gsum[t] / cnt + b2[c];
    }
}

extern "C" void kernel_launch(void* const* d_in, const int* in_sizes, int n_in,
                              void* d_out, int out_size, void* d_ws, size_t ws_size,
                              hipStream_t stream) {
    const float* x    = (const float*)d_in[0];
    const int*   ei   = (const int*)d_in[1];
    const int*   batch= (const int*)d_in[2];
    const float* W1   = (const float*)d_in[3];
    const float* b1   = (const float*)d_in[4];
    const float* W2   = (const float*)d_in[5];
    const float* b2   = (const float*)d_in[6];
    float* out = (float*)d_out;

    int N = in_sizes[0] / CH;    // 50000
    int E = in_sizes[1] / 2;     // 800000
    const int* esrc = ei;
    const int* edst = ei + E;

    // workspace carve-up (all re-initialized every call; harness poisons ws)
    char* w = (char*)d_ws;
    auto alloc = [&](size_t bytes) -> void* {
        void* p = (void*)w;
        w += (bytes + 255) & ~(size_t)255;
        return p;
    };
    float* h        = (float*)alloc((size_t)N * CH * sizeof(float));
    int*   deg      = (int*)  alloc((size_t)N * sizeof(int));
    float* dinv     = (float*)alloc((size_t)N * sizeof(float));
    int*   row_start= (int*)  alloc((size_t)(N + 1) * sizeof(int));
    int*   cursor   = (int*)  alloc((size_t)N * sizeof(int));
    int*   csr      = (int*)  alloc((size_t)E * sizeof(int));
    float* h2       = (float*)alloc((size_t)N * 2 * sizeof(float));
    int*   bsum     = (int*)  alloc(256 * sizeof(int));
    int*   boff     = (int*)  alloc(256 * sizeof(int));
    float* gsum     = (float*)alloc(128 * sizeof(float));
    int*   gcnt     = (int*)  alloc(64 * sizeof(int));

    int nbN = (N + 255) / 256;     // 196 (must be <= 256 for single-block scan)
    int nbE = (E + 255) / 256;

    k_init  <<<nbN, 256, 0, stream>>>(deg, row_start, gsum, gcnt, N, E);
    k_count <<<nbE, 256, 0, stream>>>(edst, deg, E);
    k_dinv  <<<nbN, 256, 0, stream>>>(deg, dinv, N);
    k_scan_a<<<nbN, 256, 0, stream>>>(deg, row_start, bsum, N);
    k_scan_b<<<1,   256, 0, stream>>>(bsum, boff, nbN);
    k_scan_c<<<nbN, 256, 0, stream>>>(row_start, cursor, boff, N);
    k_fill  <<<nbE, 256, 0, stream>>>(esrc, edst, cursor, csr, E);
    k_gemm1 <<<(N + 31) / 32, 256, 0, stream>>>(x, W1, dinv, h, N);
    k_layer1<<<N, 128, 0, stream>>>(h, csr, row_start, dinv, b1, W2, h2, N);
    k_layer2_pool<<<nbN, 256, 0, stream>>>(h2, csr, row_start, dinv, batch, gsum, gcnt, N);
    k_final <<<1, 128, 0, stream>>>(gsum, gcnt, b2, out);
}

// Round 3
// 262.716 us; speedup vs baseline: 1.0994x; 1.0994x over previous
//
#include <hip/hip_runtime.h>

// GCN 2-layer forward on MI355X (gfx950).
// R2 resubmit (R2 bench never ran: GPU acquisition timeout).
// h stored fp16 (halves gather HBM traffic), wave-per-node layer1 with
// shfl-broadcast neighbor lists, MFMA fp16 GEMM1, dinv merged into scan.

#define NGRAPH 64
#define CH 128

typedef float f32x4 __attribute__((ext_vector_type(4)));
typedef _Float16 f16x8 __attribute__((ext_vector_type(8)));
typedef _Float16 f16x4 __attribute__((ext_vector_type(4)));
typedef _Float16 f16x2 __attribute__((ext_vector_type(2)));

// ---------------- init ----------------
__global__ void k_init(int* __restrict__ deg, int* __restrict__ row_start,
                       float* __restrict__ gsum, int* __restrict__ gcnt,
                       int N, int E) {
    int i = blockIdx.x * blockDim.x + threadIdx.x;
    if (i < N) deg[i] = 1;                 // self-loop
    if (i == 0) row_start[N] = E;          // sentinel (non-self edge total)
    if (i < 2 * NGRAPH) gsum[i] = 0.f;
    if (i < NGRAPH) gcnt[i] = 0;
}

// ---------------- degree count ----------------
__global__ void k_count(const int* __restrict__ dst, int* __restrict__ deg, int E) {
    int i = blockIdx.x * blockDim.x + threadIdx.x;
    if (i < E) atomicAdd(&deg[dst[i]], 1);
}

// ---------------- scan pass A (+ dinv fused) ----------------
__global__ void k_scan_a(const int* __restrict__ deg, int* __restrict__ row_start,
                         int* __restrict__ bsum, float* __restrict__ dinv, int N) {
    __shared__ int tmp[256];
    int t = threadIdx.x;
    int i = blockIdx.x * 256 + t;
    int d = (i < N) ? deg[i] : 1;
    if (i < N) dinv[i] = rsqrtf((float)d);
    int v = (i < N) ? (d - 1) : 0;        // edges excluding self-loop
    int val = v;
    tmp[t] = val;
    __syncthreads();
    for (int off = 1; off < 256; off <<= 1) {
        int add = (t >= off) ? tmp[t - off] : 0;
        __syncthreads();
        val += add;
        tmp[t] = val;
        __syncthreads();
    }
    if (i < N) row_start[i] = val - v;     // exclusive
    if (t == 255) bsum[blockIdx.x] = val;  // block total
}

__global__ void k_scan_b(const int* __restrict__ bsum, int* __restrict__ boff, int nb) {
    __shared__ int tmp[256];
    int t = threadIdx.x;
    int v = (t < nb) ? bsum[t] : 0;
    int val = v;
    tmp[t] = val;
    __syncthreads();
    for (int off = 1; off < 256; off <<= 1) {
        int add = (t >= off) ? tmp[t - off] : 0;
        __syncthreads();
        val += add;
        tmp[t] = val;
        __syncthreads();
    }
    if (t < nb) boff[t] = val - v;
}

__global__ void k_scan_c(int* __restrict__ row_start, int* __restrict__ cursor,
                         const int* __restrict__ boff, int N) {
    int i = blockIdx.x * blockDim.x + threadIdx.x;
    if (i < N) {
        int rs = row_start[i] + boff[blockIdx.x];
        row_start[i] = rs;
        cursor[i] = rs;
    }
}

// ---------------- CSR fill (counting sort by dst) ----------------
__global__ void k_fill(const int* __restrict__ src, const int* __restrict__ dst,
                       int* __restrict__ cursor, int* __restrict__ csr, int E) {
    int i = blockIdx.x * blockDim.x + threadIdx.x;
    if (i < E) {
        int d = dst[i];
        int p = atomicAdd(&cursor[d], 1);
        csr[p] = src[i];
    }
}

// ---------------- GEMM1 (MFMA fp16): h[n] = fp16((x[n] @ W1) * dinv[n]) ----------------
// block = 256 thr (4 waves), 64 rows of X, full 128 output cols.
// LDS: Xs 64x136 halves (17.4 KB, reused as epilogue staging), Ws 128x136 (34.8 KB).
__global__ __launch_bounds__(256) void k_gemm1(const float* __restrict__ X,
                                               const float* __restrict__ W1,
                                               const float* __restrict__ dinv,
                                               _Float16* __restrict__ H, int N) {
    __shared__ _Float16 Xs[64 * 136];   // stride 136 halves = 272 B (17x16B: aligned + bank-spread)
    __shared__ _Float16 Ws[128 * 136];  // transposed: Ws[col][k]
    int t = threadIdx.x;
    int row0 = blockIdx.x * 64;
    const float4* Xv = (const float4*)X;
    const float4* Wv = (const float4*)W1;

    // stage X tile (fp32 -> fp16), coalesced float4 reads
    #pragma unroll
    for (int i = 0; i < 8; i++) {
        int gi = t + i * 256;            // 2048 float4
        int r = gi >> 5, c4 = gi & 31;
        int gr = row0 + r;
        float4 v = (gr < N) ? Xv[(size_t)gr * 32 + c4] : make_float4(0.f, 0.f, 0.f, 0.f);
        f16x4 hv = {(_Float16)v.x, (_Float16)v.y, (_Float16)v.z, (_Float16)v.w};
        *(f16x4*)&Xs[r * 136 + 4 * c4] = hv;
    }
    // stage W1 transposed via 4x4 register blocks
    #pragma unroll
    for (int i = 0; i < 4; i++) {
        int b = t + i * 256;             // 1024 4x4 blocks
        int kb = b >> 5, cb = b & 31;    // k0=4kb, c0=4cb
        float4 r0 = Wv[(4 * kb + 0) * 32 + cb];
        float4 r1 = Wv[(4 * kb + 1) * 32 + cb];
        float4 r2 = Wv[(4 * kb + 2) * 32 + cb];
        float4 r3 = Wv[(4 * kb + 3) * 32 + cb];
        f16x4 c0v = {(_Float16)r0.x, (_Float16)r1.x, (_Float16)r2.x, (_Float16)r3.x};
        f16x4 c1v = {(_Float16)r0.y, (_Float16)r1.y, (_Float16)r2.y, (_Float16)r3.y};
        f16x4 c2v = {(_Float16)r0.z, (_Float16)r1.z, (_Float16)r2.z, (_Float16)r3.z};
        f16x4 c3v = {(_Float16)r0.w, (_Float16)r1.w, (_Float16)r2.w, (_Float16)r3.w};
        *(f16x4*)&Ws[(4 * cb + 0) * 136 + 4 * kb] = c0v;
        *(f16x4*)&Ws[(4 * cb + 1) * 136 + 4 * kb] = c1v;
        *(f16x4*)&Ws[(4 * cb + 2) * 136 + 4 * kb] = c2v;
        *(f16x4*)&Ws[(4 * cb + 3) * 136 + 4 * kb] = c3v;
    }
    __syncthreads();

    int w = t >> 6, l = t & 63;
    int r0w = w * 16;                    // wave's 16 rows
    int lr = l & 15, lk = (l >> 4) * 8;  // operand frag: lane&15 = M/N idx, upper = K
    f32x4 acc[8] = {};
    #pragma unroll
    for (int k0 = 0; k0 < 128; k0 += 32) {
        f16x8 a = *(const f16x8*)&Xs[(r0w + lr) * 136 + k0 + lk];
        #pragma unroll
        for (int c = 0; c < 8; c++) {
            f16x8 bf = *(const f16x8*)&Ws[(c * 16 + lr) * 136 + k0 + lk];
            acc[c] = __builtin_amdgcn_mfma_f32_16x16x32_f16(a, bf, acc[c], 0, 0, 0);
        }
    }
    // epilogue: scale by dinv, through LDS for coalesced fp16 stores
    float dv[4];
    #pragma unroll
    for (int q = 0; q < 4; q++) {
        int gr = row0 + r0w + (l >> 4) * 4 + q;
        dv[q] = (gr < N) ? dinv[gr] : 0.f;
    }
    __syncthreads();                     // everyone done reading Xs
    #pragma unroll
    for (int c = 0; c < 8; c++)
        #pragma unroll
        for (int q = 0; q < 4; q++)      // C/D map: col=lane&15, row=(lane>>4)*4+q
            Xs[(r0w + (l >> 4) * 4 + q) * 136 + c * 16 + lr] = (_Float16)(acc[c][q] * dv[q]);
    __syncthreads();
    f16x2* Hv = (f16x2*)H;
    #pragma unroll
    for (int i = 0; i < 16; i++) {
        int gi = t + i * 256;            // 4096 half2
        int r = gi >> 6, cp = gi & 63;
        int gr = row0 + r;
        if (gr < N) Hv[(size_t)gr * 64 + cp] = *(f16x2*)&Xs[r * 136 + 2 * cp];
    }
}

// ---------------- layer1 aggregate + bias + relu + GEMM2 fused ----------------
// one WAVE per node; lane l = channels 2l,2l+1. No LDS, no block barriers.
__global__ __launch_bounds__(256) void k_layer1(const _Float16* __restrict__ h,
                                                const int* __restrict__ csr,
                                                const int* __restrict__ row_start,
                                                const float* __restrict__ dinv,
                                                const float* __restrict__ b1,
                                                const float* __restrict__ W2,
                                                float* __restrict__ h2, int N) {
    int n = (blockIdx.x * 256 + threadIdx.x) >> 6;
    int l = threadIdx.x & 63;
    if (n >= N) return;
    const f16x2* hv = (const f16x2*)h;
    float dn = dinv[n];
    f16x2 self = hv[(size_t)n * 64 + l];
    float acc0 = (float)self.x, acc1 = (float)self.y;
    int base = row_start[n];
    int cnt = row_start[n + 1] - base;
    for (int c0 = 0; c0 < cnt; c0 += 64) {
        int m = cnt - c0; if (m > 64) m = 64;
        int idx = (c0 + l < cnt) ? csr[base + c0 + l] : 0;
        for (int j = 0; j < m; j++) {
            int s = __shfl(idx, j);
            f16x2 v = hv[(size_t)s * 64 + l];   // 256B/row coalesced gather
            acc0 += (float)v.x;
            acc1 += (float)v.y;
        }
    }
    float2 bb = ((const float2*)b1)[l];
    float v0 = fmaxf(fmaf(dn, acc0, bb.x), 0.f);
    float v1 = fmaxf(fmaf(dn, acc1, bb.y), 0.f);
    float4 w2 = ((const float4*)W2)[l];  // rows 2l,2l+1 of W2[128][2]
    float p0 = fmaf(v0, w2.x, v1 * w2.z);
    float p1 = fmaf(v0, w2.y, v1 * w2.w);
    #pragma unroll
    for (int off = 32; off; off >>= 1) {
        p0 += __shfl_xor(p0, off);
        p1 += __shfl_xor(p1, off);
    }
    if (l == 0) ((float2*)h2)[n] = make_float2(p0 * dn, p1 * dn);  // pre-scaled by dinv[n]
}

// ---------------- layer2 aggregate + global mean pool accumulate ----------------
__global__ __launch_bounds__(256) void k_layer2_pool(const float* __restrict__ h2,
                                                     const int* __restrict__ csr,
                                                     const int* __restrict__ row_start,
                                                     const float* __restrict__ dinv,
                                                     const int* __restrict__ batch,
                                                     float* __restrict__ gsum,
                                                     int* __restrict__ gcnt, int N) {
    __shared__ float ssum[2 * NGRAPH];
    __shared__ int scnt[NGRAPH];
    int t = threadIdx.x;
    if (t < 2 * NGRAPH) ssum[t] = 0.f;
    if (t < NGRAPH) scnt[t] = 0;
    __syncthreads();
    int n = blockIdx.x * blockDim.x + t;
    if (n < N) {
        const float2* h2v = (const float2*)h2;
        float dn = dinv[n];
        float2 a = h2v[n];               // self term (already *dinv[n])
        int base = row_start[n], end = row_start[n + 1];
        for (int e = base; e < end; e++) {
            float2 v = h2v[csr[e]];
            a.x += v.x;
            a.y += v.y;
        }
        a.x *= dn;
        a.y *= dn;
        int g = batch[n];
        atomicAdd(&ssum[g * 2 + 0], a.x);
        atomicAdd(&ssum[g * 2 + 1], a.y);
        atomicAdd(&scnt[g], 1);
    }
    __syncthreads();
    if (t < 2 * NGRAPH) atomicAdd(&gsum[t], ssum[t]);
    if (t < NGRAPH) atomicAdd(&gcnt[t], scnt[t]);
}

__global__ void k_final(const float* __restrict__ gsum, const int* __restrict__ gcnt,
                        const float* __restrict__ b2, float* __restrict__ out) {
    int t = threadIdx.x;   // 0..127
    if (t < 2 * NGRAPH) {
        int g = t >> 1, c = t & 1;
        float cnt = fmaxf((float)gcnt[g], 1.f);
        out[t] = gsum[t] / cnt + b2[c];
    }
}

extern "C" void kernel_launch(void* const* d_in, const int* in_sizes, int n_in,
                              void* d_out, int out_size, void* d_ws, size_t ws_size,
                              hipStream_t stream) {
    const float* x     = (const float*)d_in[0];
    const int*   ei    = (const int*)d_in[1];
    const int*   batch = (const int*)d_in[2];
    const float* W1    = (const float*)d_in[3];
    const float* b1    = (const float*)d_in[4];
    const float* W2    = (const float*)d_in[5];
    const float* b2    = (const float*)d_in[6];
    float* out = (float*)d_out;

    int N = in_sizes[0] / CH;    // 50000
    int E = in_sizes[1] / 2;     // 800000
    const int* esrc = ei;
    const int* edst = ei + E;

    char* w = (char*)d_ws;
    auto alloc = [&](size_t bytes) -> void* {
        void* p = (void*)w;
        w += (bytes + 255) & ~(size_t)255;
        return p;
    };
    _Float16* h      = (_Float16*)alloc((size_t)N * CH * sizeof(_Float16));
    int* deg         = (int*)  alloc((size_t)N * sizeof(int));
    float* dinv      = (float*)alloc((size_t)N * sizeof(float));
    int* row_start   = (int*)  alloc((size_t)(N + 1) * sizeof(int));
    int* cursor      = (int*)  alloc((size_t)N * sizeof(int));
    int* csr         = (int*)  alloc((size_t)E * sizeof(int));
    float* h2        = (float*)alloc((size_t)N * 2 * sizeof(float));
    int* bsum        = (int*)  alloc(256 * sizeof(int));
    int* boff        = (int*)  alloc(256 * sizeof(int));
    float* gsum      = (float*)alloc(128 * sizeof(float));
    int* gcnt        = (int*)  alloc(64 * sizeof(int));

    int nbN = (N + 255) / 256;     // 196 (<=256 so single-block scan_b works)
    int nbE = (E + 255) / 256;

    k_init  <<<nbN, 256, 0, stream>>>(deg, row_start, gsum, gcnt, N, E);
    k_count <<<nbE, 256, 0, stream>>>(edst, deg, E);
    k_scan_a<<<nbN, 256, 0, stream>>>(deg, row_start, bsum, dinv, N);
    k_scan_b<<<1,   256, 0, stream>>>(bsum, boff, nbN);
    k_scan_c<<<nbN, 256, 0, stream>>>(row_start, cursor, boff, N);
    k_fill  <<<nbE, 256, 0, stream>>>(esrc, edst, cursor, csr, E);
    k_gemm1 <<<(N + 63) / 64, 256, 0, stream>>>(x, W1, dinv, h, N);
    k_layer1<<<(N * 64 + 255) / 256, 256, 0, stream>>>(h, csr, row_start, dinv, b1, W2, h2, N);
    k_layer2_pool<<<nbN, 256, 0, stream>>>(h2, csr, row_start, dinv, batch, gsum, gcnt, N);
    k_final <<<1, 128, 0, stream>>>(gsum, gcnt, b2, out);
}

// Round 4
// 239.093 us; speedup vs baseline: 1.2080x; 1.0988x over previous
//
#include <hip/hip_runtime.h>

// GCN 2-layer forward on MI355X (gfx950).
// R4: k_layer1 gather unrolled x8 (8 independent row-gathers in flight per wave)
// to attack gather-latency bound (R3 counters: 17% HBM BW, VALUBusy 28%, MLP=1).
// Everything else unchanged from R3 for attribution.

#define NGRAPH 64
#define CH 128

typedef float f32x4 __attribute__((ext_vector_type(4)));
typedef _Float16 f16x8 __attribute__((ext_vector_type(8)));
typedef _Float16 f16x4 __attribute__((ext_vector_type(4)));
typedef _Float16 f16x2 __attribute__((ext_vector_type(2)));

// ---------------- init ----------------
__global__ void k_init(int* __restrict__ deg, int* __restrict__ row_start,
                       float* __restrict__ gsum, int* __restrict__ gcnt,
                       int N, int E) {
    int i = blockIdx.x * blockDim.x + threadIdx.x;
    if (i < N) deg[i] = 1;                 // self-loop
    if (i == 0) row_start[N] = E;          // sentinel (non-self edge total)
    if (i < 2 * NGRAPH) gsum[i] = 0.f;
    if (i < NGRAPH) gcnt[i] = 0;
}

// ---------------- degree count ----------------
__global__ void k_count(const int* __restrict__ dst, int* __restrict__ deg, int E) {
    int i = blockIdx.x * blockDim.x + threadIdx.x;
    if (i < E) atomicAdd(&deg[dst[i]], 1);
}

// ---------------- scan pass A (+ dinv fused) ----------------
__global__ void k_scan_a(const int* __restrict__ deg, int* __restrict__ row_start,
                         int* __restrict__ bsum, float* __restrict__ dinv, int N) {
    __shared__ int tmp[256];
    int t = threadIdx.x;
    int i = blockIdx.x * 256 + t;
    int d = (i < N) ? deg[i] : 1;
    if (i < N) dinv[i] = rsqrtf((float)d);
    int v = (i < N) ? (d - 1) : 0;        // edges excluding self-loop
    int val = v;
    tmp[t] = val;
    __syncthreads();
    for (int off = 1; off < 256; off <<= 1) {
        int add = (t >= off) ? tmp[t - off] : 0;
        __syncthreads();
        val += add;
        tmp[t] = val;
        __syncthreads();
    }
    if (i < N) row_start[i] = val - v;     // exclusive
    if (t == 255) bsum[blockIdx.x] = val;  // block total
}

__global__ void k_scan_b(const int* __restrict__ bsum, int* __restrict__ boff, int nb) {
    __shared__ int tmp[256];
    int t = threadIdx.x;
    int v = (t < nb) ? bsum[t] : 0;
    int val = v;
    tmp[t] = val;
    __syncthreads();
    for (int off = 1; off < 256; off <<= 1) {
        int add = (t >= off) ? tmp[t - off] : 0;
        __syncthreads();
        val += add;
        tmp[t] = val;
        __syncthreads();
    }
    if (t < nb) boff[t] = val - v;
}

__global__ void k_scan_c(int* __restrict__ row_start, int* __restrict__ cursor,
                         const int* __restrict__ boff, int N) {
    int i = blockIdx.x * blockDim.x + threadIdx.x;
    if (i < N) {
        int rs = row_start[i] + boff[blockIdx.x];
        row_start[i] = rs;
        cursor[i] = rs;
    }
}

// ---------------- CSR fill (counting sort by dst) ----------------
__global__ void k_fill(const int* __restrict__ src, const int* __restrict__ dst,
                       int* __restrict__ cursor, int* __restrict__ csr, int E) {
    int i = blockIdx.x * blockDim.x + threadIdx.x;
    if (i < E) {
        int d = dst[i];
        int p = atomicAdd(&cursor[d], 1);
        csr[p] = src[i];
    }
}

// ---------------- GEMM1 (MFMA fp16): h[n] = fp16((x[n] @ W1) * dinv[n]) ----------------
__global__ __launch_bounds__(256) void k_gemm1(const float* __restrict__ X,
                                               const float* __restrict__ W1,
                                               const float* __restrict__ dinv,
                                               _Float16* __restrict__ H, int N) {
    __shared__ _Float16 Xs[64 * 136];   // 272B row stride (16B-aligned)
    __shared__ _Float16 Ws[128 * 136];  // transposed: Ws[col][k]
    int t = threadIdx.x;
    int row0 = blockIdx.x * 64;
    const float4* Xv = (const float4*)X;
    const float4* Wv = (const float4*)W1;

    #pragma unroll
    for (int i = 0; i < 8; i++) {
        int gi = t + i * 256;            // 2048 float4
        int r = gi >> 5, c4 = gi & 31;
        int gr = row0 + r;
        float4 v = (gr < N) ? Xv[(size_t)gr * 32 + c4] : make_float4(0.f, 0.f, 0.f, 0.f);
        f16x4 hv = {(_Float16)v.x, (_Float16)v.y, (_Float16)v.z, (_Float16)v.w};
        *(f16x4*)&Xs[r * 136 + 4 * c4] = hv;
    }
    #pragma unroll
    for (int i = 0; i < 4; i++) {
        int b = t + i * 256;             // 1024 4x4 blocks
        int kb = b >> 5, cb = b & 31;
        float4 r0 = Wv[(4 * kb + 0) * 32 + cb];
        float4 r1 = Wv[(4 * kb + 1) * 32 + cb];
        float4 r2 = Wv[(4 * kb + 2) * 32 + cb];
        float4 r3 = Wv[(4 * kb + 3) * 32 + cb];
        f16x4 c0v = {(_Float16)r0.x, (_Float16)r1.x, (_Float16)r2.x, (_Float16)r3.x};
        f16x4 c1v = {(_Float16)r0.y, (_Float16)r1.y, (_Float16)r2.y, (_Float16)r3.y};
        f16x4 c2v = {(_Float16)r0.z, (_Float16)r1.z, (_Float16)r2.z, (_Float16)r3.z};
        f16x4 c3v = {(_Float16)r0.w, (_Float16)r1.w, (_Float16)r2.w, (_Float16)r3.w};
        *(f16x4*)&Ws[(4 * cb + 0) * 136 + 4 * kb] = c0v;
        *(f16x4*)&Ws[(4 * cb + 1) * 136 + 4 * kb] = c1v;
        *(f16x4*)&Ws[(4 * cb + 2) * 136 + 4 * kb] = c2v;
        *(f16x4*)&Ws[(4 * cb + 3) * 136 + 4 * kb] = c3v;
    }
    __syncthreads();

    int w = t >> 6, l = t & 63;
    int r0w = w * 16;
    int lr = l & 15, lk = (l >> 4) * 8;
    f32x4 acc[8] = {};
    #pragma unroll
    for (int k0 = 0; k0 < 128; k0 += 32) {
        f16x8 a = *(const f16x8*)&Xs[(r0w + lr) * 136 + k0 + lk];
        #pragma unroll
        for (int c = 0; c < 8; c++) {
            f16x8 bf = *(const f16x8*)&Ws[(c * 16 + lr) * 136 + k0 + lk];
            acc[c] = __builtin_amdgcn_mfma_f32_16x16x32_f16(a, bf, acc[c], 0, 0, 0);
        }
    }
    float dv[4];
    #pragma unroll
    for (int q = 0; q < 4; q++) {
        int gr = row0 + r0w + (l >> 4) * 4 + q;
        dv[q] = (gr < N) ? dinv[gr] : 0.f;
    }
    __syncthreads();
    #pragma unroll
    for (int c = 0; c < 8; c++)
        #pragma unroll
        for (int q = 0; q < 4; q++)      // C/D map: col=lane&15, row=(lane>>4)*4+q
            Xs[(r0w + (l >> 4) * 4 + q) * 136 + c * 16 + lr] = (_Float16)(acc[c][q] * dv[q]);
    __syncthreads();
    f16x2* Hv = (f16x2*)H;
    #pragma unroll
    for (int i = 0; i < 16; i++) {
        int gi = t + i * 256;            // 4096 half2
        int r = gi >> 6, cp = gi & 63;
        int gr = row0 + r;
        if (gr < N) Hv[(size_t)gr * 64 + cp] = *(f16x2*)&Xs[r * 136 + 2 * cp];
    }
}

// ---------------- layer1 aggregate + bias + relu + GEMM2 fused ----------------
// one WAVE per node; lane l = channels 2l,2l+1. Gather unrolled x8 for MLP.
__global__ __launch_bounds__(256) void k_layer1(const _Float16* __restrict__ h,
                                                const int* __restrict__ csr,
                                                const int* __restrict__ row_start,
                                                const float* __restrict__ dinv,
                                                const float* __restrict__ b1,
                                                const float* __restrict__ W2,
                                                float* __restrict__ h2, int N) {
    int n = (blockIdx.x * 256 + threadIdx.x) >> 6;
    int l = threadIdx.x & 63;
    if (n >= N) return;
    const f16x2* hv = (const f16x2*)h;
    float dn = dinv[n];
    f16x2 self = hv[(size_t)n * 64 + l];
    float acc0 = (float)self.x, acc1 = (float)self.y;
    int base = row_start[n];
    int cnt = row_start[n + 1] - base;
    for (int c0 = 0; c0 < cnt; c0 += 64) {
        int m = cnt - c0; if (m > 64) m = 64;
        int idx = (c0 + l < cnt) ? csr[base + c0 + l] : 0;
        int j = 0;
        int jm = m & ~7;
        for (; j < jm; j += 8) {         // 8 independent 256B row-gathers in flight
            int s0 = __shfl(idx, j + 0), s1 = __shfl(idx, j + 1);
            int s2 = __shfl(idx, j + 2), s3 = __shfl(idx, j + 3);
            int s4 = __shfl(idx, j + 4), s5 = __shfl(idx, j + 5);
            int s6 = __shfl(idx, j + 6), s7 = __shfl(idx, j + 7);
            f16x2 v0 = hv[(size_t)s0 * 64 + l];
            f16x2 v1 = hv[(size_t)s1 * 64 + l];
            f16x2 v2 = hv[(size_t)s2 * 64 + l];
            f16x2 v3 = hv[(size_t)s3 * 64 + l];
            f16x2 v4 = hv[(size_t)s4 * 64 + l];
            f16x2 v5 = hv[(size_t)s5 * 64 + l];
            f16x2 v6 = hv[(size_t)s6 * 64 + l];
            f16x2 v7 = hv[(size_t)s7 * 64 + l];
            acc0 += (float)v0.x; acc1 += (float)v0.y;
            acc0 += (float)v1.x; acc1 += (float)v1.y;
            acc0 += (float)v2.x; acc1 += (float)v2.y;
            acc0 += (float)v3.x; acc1 += (float)v3.y;
            acc0 += (float)v4.x; acc1 += (float)v4.y;
            acc0 += (float)v5.x; acc1 += (float)v5.y;
            acc0 += (float)v6.x; acc1 += (float)v6.y;
            acc0 += (float)v7.x; acc1 += (float)v7.y;
        }
        for (; j < m; ++j) {
            int s = __shfl(idx, j);
            f16x2 v = hv[(size_t)s * 64 + l];
            acc0 += (float)v.x; acc1 += (float)v.y;
        }
    }
    float2 bb = ((const float2*)b1)[l];
    float v0 = fmaxf(fmaf(dn, acc0, bb.x), 0.f);
    float v1 = fmaxf(fmaf(dn, acc1, bb.y), 0.f);
    float4 w2 = ((const float4*)W2)[l];  // rows 2l,2l+1 of W2[128][2]
    float p0 = fmaf(v0, w2.x, v1 * w2.z);
    float p1 = fmaf(v0, w2.y, v1 * w2.w);
    #pragma unroll
    for (int off = 32; off; off >>= 1) {
        p0 += __shfl_xor(p0, off);
        p1 += __shfl_xor(p1, off);
    }
    if (l == 0) ((float2*)h2)[n] = make_float2(p0 * dn, p1 * dn);  // pre-scaled by dinv[n]
}

// ---------------- layer2 aggregate + global mean pool accumulate ----------------
__global__ __launch_bounds__(256) void k_layer2_pool(const float* __restrict__ h2,
                                                     const int* __restrict__ csr,
                                                     const int* __restrict__ row_start,
                                                     const float* __restrict__ dinv,
                                                     const int* __restrict__ batch,
                                                     float* __restrict__ gsum,
                                                     int* __restrict__ gcnt, int N) {
    __shared__ float ssum[2 * NGRAPH];
    __shared__ int scnt[NGRAPH];
    int t = threadIdx.x;
    if (t < 2 * NGRAPH) ssum[t] = 0.f;
    if (t < NGRAPH) scnt[t] = 0;
    __syncthreads();
    int n = blockIdx.x * blockDim.x + t;
    if (n < N) {
        const float2* h2v = (const float2*)h2;
        float dn = dinv[n];
        float2 a = h2v[n];               // self term (already *dinv[n])
        int base = row_start[n], end = row_start[n + 1];
        for (int e = base; e < end; e++) {
            float2 v = h2v[csr[e]];
            a.x += v.x;
            a.y += v.y;
        }
        a.x *= dn;
        a.y *= dn;
        int g = batch[n];
        atomicAdd(&ssum[g * 2 + 0], a.x);
        atomicAdd(&ssum[g * 2 + 1], a.y);
        atomicAdd(&scnt[g], 1);
    }
    __syncthreads();
    if (t < 2 * NGRAPH) atomicAdd(&gsum[t], ssum[t]);
    if (t < NGRAPH) atomicAdd(&gcnt[t], scnt[t]);
}

__global__ void k_final(const float* __restrict__ gsum, const int* __restrict__ gcnt,
                        const float* __restrict__ b2, float* __restrict__ out) {
    int t = threadIdx.x;   // 0..127
    if (t < 2 * NGRAPH) {
        int g = t >> 1, c = t & 1;
        float cnt = fmaxf((float)gcnt[g], 1.f);
        out[t] = gsum[t] / cnt + b2[c];
    }
}

extern "C" void kernel_launch(void* const* d_in, const int* in_sizes, int n_in,
                              void* d_out, int out_size, void* d_ws, size_t ws_size,
                              hipStream_t stream) {
    const float* x     = (const float*)d_in[0];
    const int*   ei    = (const int*)d_in[1];
    const int*   batch = (const int*)d_in[2];
    const float* W1    = (const float*)d_in[3];
    const float* b1    = (const float*)d_in[4];
    const float* W2    = (const float*)d_in[5];
    const float* b2    = (const float*)d_in[6];
    float* out = (float*)d_out;

    int N = in_sizes[0] / CH;    // 50000
    int E = in_sizes[1] / 2;     // 800000
    const int* esrc = ei;
    const int* edst = ei + E;

    char* w = (char*)d_ws;
    auto alloc = [&](size_t bytes) -> void* {
        void* p = (void*)w;
        w += (bytes + 255) & ~(size_t)255;
        return p;
    };
    _Float16* h      = (_Float16*)alloc((size_t)N * CH * sizeof(_Float16));
    int* deg         = (int*)  alloc((size_t)N * sizeof(int));
    float* dinv      = (float*)alloc((size_t)N * sizeof(float));
    int* row_start   = (int*)  alloc((size_t)(N + 1) * sizeof(int));
    int* cursor      = (int*)  alloc((size_t)N * sizeof(int));
    int* csr         = (int*)  alloc((size_t)E * sizeof(int));
    float* h2        = (float*)alloc((size_t)N * 2 * sizeof(float));
    int* bsum        = (int*)  alloc(256 * sizeof(int));
    int* boff        = (int*)  alloc(256 * sizeof(int));
    float* gsum      = (float*)alloc(128 * sizeof(float));
    int* gcnt        = (int*)  alloc(64 * sizeof(int));

    int nbN = (N + 255) / 256;     // 196 (<=256 so single-block scan_b works)
    int nbE = (E + 255) / 256;

    k_init  <<<nbN, 256, 0, stream>>>(deg, row_start, gsum, gcnt, N, E);
    k_count <<<nbE, 256, 0, stream>>>(edst, deg, E);
    k_scan_a<<<nbN, 256, 0, stream>>>(deg, row_start, bsum, dinv, N);
    k_scan_b<<<1,   256, 0, stream>>>(bsum, boff, nbN);
    k_scan_c<<<nbN, 256, 0, stream>>>(row_start, cursor, boff, N);
    k_fill  <<<nbE, 256, 0, stream>>>(esrc, edst, cursor, csr, E);
    k_gemm1 <<<(N + 63) / 64, 256, 0, stream>>>(x, W1, dinv, h, N);
    k_layer1<<<(N * 64 + 255) / 256, 256, 0, stream>>>(h, csr, row_start, dinv, b1, W2, h2, N);
    k_layer2_pool<<<nbN, 256, 0, stream>>>(h2, csr, row_start, dinv, batch, gsum, gcnt, N);
    k_final <<<1, 128, 0, stream>>>(gsum, gcnt, b2, out);
}